// Round 1
// baseline (1254.234 us; speedup 1.0000x reference)
//
#include <hip/hip_runtime.h>
#include <hip/hip_bf16.h>
#include <stdint.h>

#define HD   1024
#define BB   64
#define SS   2048
#define MT   (BB*SS)          // 131072 rows
#define NEGV -10000000000.0f

typedef __attribute__((ext_vector_type(8))) short bf16x8;
typedef __attribute__((ext_vector_type(4))) float f32x4;
typedef __attribute__((ext_vector_type(4))) int   i32x4;

__device__ __forceinline__ void gll16(const void* g, void* l) {
  __builtin_amdgcn_global_load_lds((const __attribute__((address_space(1))) void*)g,
                                   (__attribute__((address_space(3))) void*)l, 16, 0, 0);
}

__device__ __forceinline__ float tanh_fast(float x) {
  float e = __expf(2.0f * x);
  return 1.0f - 2.0f / (e + 1.0f);
}

// ---------------------------------------------------------------------------
// Kernel 1: re-tile We = W_attn[H:2H] into bf16, transposed + XOR-swizzled.
// Output layout: tile (nt in [0,8), kc in [0,16)) is 8192 contiguous bf16:
//   out[(nt*16+kc)*8192 + nl*64 + j*8 + e] = We[kc*64 + (j^(nl&7))*8 + e][nt*128+nl]
// so the GEMM can global_load_lds the tile linearly and read B-fragments
// (8 consecutive k per lane) with only 2-way bank aliasing (free).
// ---------------------------------------------------------------------------
__global__ void prep_we(const float* __restrict__ Wattn, __hip_bfloat16* __restrict__ out) {
  __shared__ float st[64][132];
  int tid = threadIdx.x;
  int nt = blockIdx.x >> 4, kc = blockIdx.x & 15;
  const float* src = Wattn + (size_t)(HD + kc*64)*HD + nt*128;
  #pragma unroll 4
  for (int i = 0; i < 32; ++i) {
    int s = i*256 + tid;
    int kk = s >> 7, nn = s & 127;
    st[kk][nn] = src[(size_t)kk*HD + nn];
  }
  __syncthreads();
  size_t base = (size_t)blockIdx.x * 8192;
  #pragma unroll 4
  for (int i = 0; i < 32; ++i) {
    int lin = i*256 + tid;
    int nl = lin >> 6, j = (lin >> 3) & 7, e = lin & 7;
    int kk = ((j ^ (nl & 7)) << 3) + e;
    out[base + lin] = __float2bfloat16(st[kk][nl]);
  }
}

// ---------------------------------------------------------------------------
// Kernel 2: dpb[b][n] = b_attn[n] + sum_h dec[b][h] * Wd[h][n]   (all fp32)
// ---------------------------------------------------------------------------
__global__ void prep_dpb(const float* __restrict__ dec, const float* __restrict__ Wattn,
                         const float* __restrict__ battn, float* __restrict__ dpb) {
  __shared__ float dh[HD];
  int tid = threadIdx.x;
  int b = blockIdx.y;
  int n = blockIdx.x*256 + tid;
  #pragma unroll
  for (int i = 0; i < 4; ++i) dh[i*256 + tid] = dec[b*HD + i*256 + tid];
  __syncthreads();
  float acc = battn[n];
  #pragma unroll 8
  for (int h = 0; h < HD; ++h) acc += dh[h] * Wattn[(size_t)h*HD + n];
  dpb[b*HD + n] = acc;
}

// ---------------------------------------------------------------------------
// Kernel 3: fused GEMM  C = E@We  ->  tanh(C + dpb) . v_w  -> atomicAdd logits
// 128x128 tile, BK=64, 256 threads (4 waves, each 64x64 via 4x4 16x16x32 MFMA)
// A: fp32 global -> VGPR cvt bf16 -> padded LDS (row stride 72 elems)
// B: pre-tiled bf16 -> global_load_lds (width 16), XOR-swizzled in prep
// ---------------------------------------------------------------------------
__global__ void __launch_bounds__(256) gemm_fused(
    const float* __restrict__ E, const __hip_bfloat16* __restrict__ Wt,
    const float* __restrict__ dpb, const float* __restrict__ vw,
    float* __restrict__ logits) {
  __shared__ __align__(16) short Al[128*72];
  __shared__ __align__(16) short Bl[128*64];
  __shared__ float red[128];

  int tid = threadIdx.x;
  int lane = tid & 63, wid = tid >> 6;
  int wm = wid & 1, wn = wid >> 1;
  int bm = blockIdx.x >> 3, bn = blockIdx.x & 7;   // 8 consecutive blocks share bm -> A-tile L3 reuse
  int m0 = bm << 7, n0 = bn << 7;
  int lane15 = lane & 15, kg = lane >> 4;

  f32x4 acc[4][4];
  #pragma unroll
  for (int a = 0; a < 4; ++a)
    #pragma unroll
    for (int c = 0; c < 4; ++c) acc[a][c] = (f32x4){0.f, 0.f, 0.f, 0.f};

  for (int kc = 0; kc < 16; ++kc) {
    // --- B tile: 16 KB linear copy via global_load_lds (per-wave uniform LDS base)
    const char* bt = (const char*)Wt + ((size_t)(bn*16 + kc) * 8192) * 2;
    #pragma unroll
    for (int i = 0; i < 4; ++i) {
      int segbase = (wid*4 + i) * 64;
      gll16(bt + (size_t)(segbase + lane)*16, (char*)Bl + segbase*16);
    }
    // --- A tile: 128 rows x 64 k fp32 -> bf16 -> LDS
    const float* Eg = E + (m0*HD + kc*64);
    #pragma unroll
    for (int i = 0; i < 8; ++i) {
      int s = i*256 + tid;
      int r = s >> 4, q = s & 15;
      f32x4 v = *(const f32x4*)(Eg + r*HD + q*4);
      union { __hip_bfloat162 h[2]; unsigned long long u; } cv;
      cv.h[0] = __float22bfloat162_rn(make_float2(v.x, v.y));
      cv.h[1] = __float22bfloat162_rn(make_float2(v.z, v.w));
      *(unsigned long long*)&Al[r*72 + q*4] = cv.u;
    }
    __syncthreads();
    #pragma unroll
    for (int kh = 0; kh < 2; ++kh) {
      bf16x8 af[4], bfr[4];
      #pragma unroll
      for (int mf = 0; mf < 4; ++mf) {
        int row = wm*64 + mf*16 + lane15;
        af[mf] = *(const bf16x8*)&Al[row*72 + kh*32 + kg*8];
      }
      #pragma unroll
      for (int nf = 0; nf < 4; ++nf) {
        int nl = wn*64 + nf*16 + lane15;
        int jj = kh*4 + kg;
        bfr[nf] = *(const bf16x8*)&Bl[nl*64 + ((jj ^ (nl & 7)) << 3)];
      }
      #pragma unroll
      for (int mf = 0; mf < 4; ++mf)
        #pragma unroll
        for (int nf = 0; nf < 4; ++nf)
          acc[mf][nf] = __builtin_amdgcn_mfma_f32_16x16x32_bf16(af[mf], bfr[nf], acc[mf][nf], 0, 0, 0);
    }
    __syncthreads();
  }

  // --- epilogue: energy = tanh(acc + dpb); partial = energy . v_w over this 128-col slice
  int bidx = m0 >> 11;             // all 128 rows of this tile share one batch (2048 % 128 == 0)
  float dpv[4], vwv[4];
  #pragma unroll
  for (int nf = 0; nf < 4; ++nf) {
    int n = n0 + wn*64 + nf*16 + lane15;
    dpv[nf] = dpb[bidx*HD + n];
    vwv[nf] = vw[n];
  }
  if (tid < 128) red[tid] = 0.0f;
  __syncthreads();
  #pragma unroll
  for (int mf = 0; mf < 4; ++mf) {
    #pragma unroll
    for (int r = 0; r < 4; ++r) {
      float s = 0.0f;
      #pragma unroll
      for (int nf = 0; nf < 4; ++nf) {
        float x = acc[mf][nf][r] + dpv[nf];
        s += tanh_fast(x) * vwv[nf];
      }
      // sum across the 16 lanes (lane15 = column index) holding this row
      s += __shfl_xor(s, 1); s += __shfl_xor(s, 2);
      s += __shfl_xor(s, 4); s += __shfl_xor(s, 8);
      if (lane15 == 0) atomicAdd(&red[wm*64 + mf*16 + kg*4 + r], s);
    }
  }
  __syncthreads();
  if (tid < 128) atomicAdd(&logits[m0 + tid], red[tid]);
}

// ---------------------------------------------------------------------------
// Kernel 4: masked softmax over S per batch row.  mask==1 -> -1e10 (masked OUT)
// ---------------------------------------------------------------------------
__global__ void softmax_k(const float* __restrict__ logits, const int* __restrict__ mask,
                          float* __restrict__ out) {
  __shared__ float smax[4];
  __shared__ float ssum[4];
  int tid = threadIdx.x, lane = tid & 63, wid = tid >> 6;
  int b = blockIdx.x;
  const float* lg = logits + b*SS;
  const int*   mk = mask   + b*SS;
  f32x4 l0 = *(const f32x4*)(lg + tid*8);
  f32x4 l1 = *(const f32x4*)(lg + tid*8 + 4);
  i32x4 q0 = *(const i32x4*)(mk + tid*8);
  i32x4 q1 = *(const i32x4*)(mk + tid*8 + 4);
  float v[8];
  v[0] = (q0.x == 1) ? NEGV : l0.x;  v[1] = (q0.y == 1) ? NEGV : l0.y;
  v[2] = (q0.z == 1) ? NEGV : l0.z;  v[3] = (q0.w == 1) ? NEGV : l0.w;
  v[4] = (q1.x == 1) ? NEGV : l1.x;  v[5] = (q1.y == 1) ? NEGV : l1.y;
  v[6] = (q1.z == 1) ? NEGV : l1.z;  v[7] = (q1.w == 1) ? NEGV : l1.w;
  float mx = v[0];
  #pragma unroll
  for (int i = 1; i < 8; ++i) mx = fmaxf(mx, v[i]);
  #pragma unroll
  for (int m = 1; m <= 32; m <<= 1) mx = fmaxf(mx, __shfl_xor(mx, m));
  if (lane == 0) smax[wid] = mx;
  __syncthreads();
  mx = fmaxf(fmaxf(smax[0], smax[1]), fmaxf(smax[2], smax[3]));
  float s = 0.0f;
  #pragma unroll
  for (int i = 0; i < 8; ++i) { v[i] = __expf(v[i] - mx); s += v[i]; }
  #pragma unroll
  for (int m = 1; m <= 32; m <<= 1) s += __shfl_xor(s, m);
  if (lane == 0) ssum[wid] = s;
  __syncthreads();
  s = ssum[0] + ssum[1] + ssum[2] + ssum[3];
  float inv = 1.0f / s;
  f32x4 o0 = {v[0]*inv, v[1]*inv, v[2]*inv, v[3]*inv};
  f32x4 o1 = {v[4]*inv, v[5]*inv, v[6]*inv, v[7]*inv};
  *(f32x4*)(out + b*SS + tid*8)     = o0;
  *(f32x4*)(out + b*SS + tid*8 + 4) = o1;
}

// ---------------------------------------------------------------------------
extern "C" void kernel_launch(void* const* d_in, const int* in_sizes, int n_in,
                              void* d_out, int out_size, void* d_ws, size_t ws_size,
                              hipStream_t stream) {
  const float* dec   = (const float*)d_in[0];   // (B, H)
  const float* enc   = (const float*)d_in[1];   // (B, S, H) -> (M, K) row-major
  const int*   mask  = (const int*)  d_in[2];   // (B, S)
  const float* Wattn = (const float*)d_in[3];   // (2H, H)
  const float* battn = (const float*)d_in[4];   // (H)
  const float* vw    = (const float*)d_in[5];   // (H)
  float* out = (float*)d_out;

  char* ws = (char*)d_ws;
  __hip_bfloat16* wet = (__hip_bfloat16*)ws;                          // 2 MB
  float* dpb    = (float*)(ws + (size_t)2*1024*1024);                 // 256 KB
  float* logits = (float*)(ws + (size_t)2*1024*1024 + 256*1024);      // 512 KB

  prep_we <<<128, 256, 0, stream>>>(Wattn, wet);
  prep_dpb<<<dim3(4, 64), 256, 0, stream>>>(dec, Wattn, battn, dpb);
  hipMemsetAsync(logits, 0, (size_t)MT*sizeof(float), stream);
  gemm_fused<<<8192, 256, 0, stream>>>(enc, wet, dpb, vw, logits);
  softmax_k<<<BB, 256, 0, stream>>>(logits, mask, out);
}

// Round 2
// 1201.630 us; speedup vs baseline: 1.0438x; 1.0438x over previous
//
#include <hip/hip_runtime.h>
#include <hip/hip_bf16.h>
#include <stdint.h>

#define HD   1024
#define BB   64
#define SS   2048
#define MT   (BB*SS)          // 131072 rows
#define NEGV -10000000000.0f

typedef __attribute__((ext_vector_type(8))) short bf16x8;
typedef __attribute__((ext_vector_type(4))) float f32x4;
typedef __attribute__((ext_vector_type(4))) int   i32x4;

__device__ __forceinline__ void gll16(const void* g, void* l) {
  __builtin_amdgcn_global_load_lds((const __attribute__((address_space(1))) void*)g,
                                   (__attribute__((address_space(3))) void*)l, 16, 0, 0);
}

__device__ __forceinline__ float tanh_fast(float x) {
  float e = __expf(2.0f * x);
  return 1.0f - 2.0f / (e + 1.0f);
}

// ---------------------------------------------------------------------------
// Tiled+swizzled bf16 layout (shared by A and B):
//   tile (t, kc) is 8192 contiguous bf16 (16 KB):
//     out[tilebase + l*64 + j*8 + e] = src[row = t*128 + l][k = kc*64 + (j^(l&7))*8 + e]
// GEMM stages a tile with linear global_load_lds; fragment reads
// (8 consecutive k per lane) land 2-way bank aliased (free).
// ---------------------------------------------------------------------------

// Kernel 1a: re-tile We = W_attn[H:2H]^T into that layout (transposed: "row"=n col)
__global__ void prep_we(const float* __restrict__ Wattn, __hip_bfloat16* __restrict__ out) {
  __shared__ float st[64][132];
  int tid = threadIdx.x;
  int nt = blockIdx.x >> 4, kc = blockIdx.x & 15;
  const float* src = Wattn + (size_t)(HD + kc*64)*HD + nt*128;
  #pragma unroll 4
  for (int i = 0; i < 32; ++i) {
    int s = i*256 + tid;
    int kk = s >> 7, nn = s & 127;
    st[kk][nn] = src[(size_t)kk*HD + nn];
  }
  __syncthreads();
  size_t base = (size_t)blockIdx.x * 8192;
  #pragma unroll 4
  for (int i = 0; i < 32; ++i) {
    int lin = i*256 + tid;
    int nl = lin >> 6, j = (lin >> 3) & 7, e = lin & 7;
    int kk = ((j ^ (nl & 7)) << 3) + e;
    out[base + lin] = __float2bfloat16(st[kk][nl]);
  }
}

// Kernel 1b: convert E (fp32 row-major) into the tiled bf16 layout (no transpose).
// One block per (mt, kc): 1024 units of 8 elems; each thread does 4 units.
__global__ void prep_E(const float* __restrict__ E, __hip_bfloat16* __restrict__ out) {
  int tid = threadIdx.x;
  int mt = blockIdx.x >> 4, kc = blockIdx.x & 15;
  const float* src = E + ((size_t)mt*128)*HD + kc*64;
  __hip_bfloat16* dst = out + (size_t)blockIdx.x * 8192;
  #pragma unroll
  for (int i = 0; i < 4; ++i) {
    int u = i*256 + tid;
    int ml = u >> 3, j = u & 7;
    int sk = ((j ^ (ml & 7)) << 3);
    const float* p = src + (size_t)ml*HD + sk;
    f32x4 v0 = *(const f32x4*)p;
    f32x4 v1 = *(const f32x4*)(p + 4);
    union { __hip_bfloat162 h[4]; i32x4 q; } cv;
    cv.h[0] = __float22bfloat162_rn(make_float2(v0.x, v0.y));
    cv.h[1] = __float22bfloat162_rn(make_float2(v0.z, v0.w));
    cv.h[2] = __float22bfloat162_rn(make_float2(v1.x, v1.y));
    cv.h[3] = __float22bfloat162_rn(make_float2(v1.z, v1.w));
    *(i32x4*)(dst + (size_t)u*8) = cv.q;
  }
}

// ---------------------------------------------------------------------------
// Kernel 2: dpb[b][n] = b_attn[n] + sum_h dec[b][h] * Wd[h][n]   (all fp32)
// 1024 blocks: (16 n-chunks of 64) x (64 batches); k split 4-ways per block.
// ---------------------------------------------------------------------------
__global__ void prep_dpb(const float* __restrict__ dec, const float* __restrict__ Wattn,
                         const float* __restrict__ battn, float* __restrict__ dpb) {
  __shared__ float red[4][64];
  int b = blockIdx.y, n0 = blockIdx.x*64;
  int nn = threadIdx.x & 63, kg = threadIdx.x >> 6;
  const float* wp = Wattn + (size_t)(kg*256)*HD + n0 + nn;
  const float* dp = dec + b*HD + kg*256;
  float acc = 0.0f;
  #pragma unroll 8
  for (int h = 0; h < 256; ++h) acc += dp[h] * wp[(size_t)h*HD];
  red[kg][nn] = acc;
  __syncthreads();
  if (threadIdx.x < 64) {
    int n = n0 + threadIdx.x;
    dpb[b*HD + n] = battn[n] + red[0][threadIdx.x] + red[1][threadIdx.x]
                             + red[2][threadIdx.x] + red[3][threadIdx.x];
  }
}

// ---------------------------------------------------------------------------
// XCD-aware block decode: consecutive blockIdx round-robin across 8 XCDs, so
// give each XCD a contiguous bm range with bn fastest -> the 8 blocks sharing
// an A-tile are temporally adjacent on ONE XCD (tile stays in its 4MB L2).
// ---------------------------------------------------------------------------
__device__ __forceinline__ void decode_bid(int bid, int& bm, int& bn) {
  int x = bid & 7, r = bid >> 3;
  bm = x*128 + (r >> 3);
  bn = r & 7;
}

// ---------------------------------------------------------------------------
// Kernel 3 (fast): GEMM C = E@We with BOTH tiles staged via global_load_lds
// from pre-tiled bf16. 128x128 tile, BK=64, 4 waves, 4x4 frags of 16x16x32.
// Fused epilogue: tanh(C + dpb) . v_w -> atomicAdd logits.
// ---------------------------------------------------------------------------
__global__ void __launch_bounds__(256) gemm_fused_bf(
    const __hip_bfloat16* __restrict__ At, const __hip_bfloat16* __restrict__ Wt,
    const float* __restrict__ dpb, const float* __restrict__ vw,
    float* __restrict__ logits) {
  __shared__ __align__(16) short Al[128*64];
  __shared__ __align__(16) short Bl[128*64];
  __shared__ float red[128];

  int tid = threadIdx.x;
  int lane = tid & 63, wid = tid >> 6;
  int wm = wid & 1, wn = wid >> 1;
  int bm, bn; decode_bid(blockIdx.x, bm, bn);
  int m0 = bm << 7, n0 = bn << 7;
  int lane15 = lane & 15, kg = lane >> 4;

  f32x4 acc[4][4];
  #pragma unroll
  for (int a = 0; a < 4; ++a)
    #pragma unroll
    for (int c = 0; c < 4; ++c) acc[a][c] = (f32x4){0.f, 0.f, 0.f, 0.f};

  for (int kc = 0; kc < 16; ++kc) {
    const char* at = (const char*)At + ((size_t)(bm*16 + kc) * 8192) * 2;
    const char* bt = (const char*)Wt + ((size_t)(bn*16 + kc) * 8192) * 2;
    #pragma unroll
    for (int i = 0; i < 4; ++i) {
      int segbase = (wid*4 + i) * 64;
      gll16(at + (size_t)(segbase + lane)*16, (char*)Al + segbase*16);
      gll16(bt + (size_t)(segbase + lane)*16, (char*)Bl + segbase*16);
    }
    __syncthreads();
    #pragma unroll
    for (int kh = 0; kh < 2; ++kh) {
      bf16x8 af[4], bfr[4];
      #pragma unroll
      for (int mf = 0; mf < 4; ++mf) {
        int row = wm*64 + mf*16 + lane15;
        int jj = kh*4 + kg;
        af[mf] = *(const bf16x8*)&Al[row*64 + ((jj ^ (row & 7)) << 3)];
      }
      #pragma unroll
      for (int nf = 0; nf < 4; ++nf) {
        int nl = wn*64 + nf*16 + lane15;
        int jj = kh*4 + kg;
        bfr[nf] = *(const bf16x8*)&Bl[nl*64 + ((jj ^ (nl & 7)) << 3)];
      }
      #pragma unroll
      for (int mf = 0; mf < 4; ++mf)
        #pragma unroll
        for (int nf = 0; nf < 4; ++nf)
          acc[mf][nf] = __builtin_amdgcn_mfma_f32_16x16x32_bf16(af[mf], bfr[nf], acc[mf][nf], 0, 0, 0);
    }
    __syncthreads();
  }

  int bidx = m0 >> 11;
  float dpv[4], vwv[4];
  #pragma unroll
  for (int nf = 0; nf < 4; ++nf) {
    int n = n0 + wn*64 + nf*16 + lane15;
    dpv[nf] = dpb[bidx*HD + n];
    vwv[nf] = vw[n];
  }
  if (tid < 128) red[tid] = 0.0f;
  __syncthreads();
  #pragma unroll
  for (int mf = 0; mf < 4; ++mf) {
    #pragma unroll
    for (int r = 0; r < 4; ++r) {
      float s = 0.0f;
      #pragma unroll
      for (int nf = 0; nf < 4; ++nf) {
        float x = acc[mf][nf][r] + dpv[nf];
        s += tanh_fast(x) * vwv[nf];
      }
      s += __shfl_xor(s, 1); s += __shfl_xor(s, 2);
      s += __shfl_xor(s, 4); s += __shfl_xor(s, 8);
      if (lane15 == 0) atomicAdd(&red[wm*64 + mf*16 + kg*4 + r], s);
    }
  }
  __syncthreads();
  if (tid < 128) atomicAdd(&logits[m0 + tid], red[tid]);
}

// ---------------------------------------------------------------------------
// Kernel 3 (fallback, ws too small): fp32 A staged via VGPR cvt (round-1 path,
// but with XCD-aware swizzle).
// ---------------------------------------------------------------------------
__global__ void __launch_bounds__(256) gemm_fused_f32(
    const float* __restrict__ E, const __hip_bfloat16* __restrict__ Wt,
    const float* __restrict__ dpb, const float* __restrict__ vw,
    float* __restrict__ logits) {
  __shared__ __align__(16) short Al[128*72];
  __shared__ __align__(16) short Bl[128*64];
  __shared__ float red[128];

  int tid = threadIdx.x;
  int lane = tid & 63, wid = tid >> 6;
  int wm = wid & 1, wn = wid >> 1;
  int bm, bn; decode_bid(blockIdx.x, bm, bn);
  int m0 = bm << 7, n0 = bn << 7;
  int lane15 = lane & 15, kg = lane >> 4;

  f32x4 acc[4][4];
  #pragma unroll
  for (int a = 0; a < 4; ++a)
    #pragma unroll
    for (int c = 0; c < 4; ++c) acc[a][c] = (f32x4){0.f, 0.f, 0.f, 0.f};

  for (int kc = 0; kc < 16; ++kc) {
    const char* bt = (const char*)Wt + ((size_t)(bn*16 + kc) * 8192) * 2;
    #pragma unroll
    for (int i = 0; i < 4; ++i) {
      int segbase = (wid*4 + i) * 64;
      gll16(bt + (size_t)(segbase + lane)*16, (char*)Bl + segbase*16);
    }
    const float* Eg = E + (m0*HD + kc*64);
    #pragma unroll
    for (int i = 0; i < 8; ++i) {
      int s = i*256 + tid;
      int r = s >> 4, q = s & 15;
      f32x4 v = *(const f32x4*)(Eg + r*HD + q*4);
      union { __hip_bfloat162 h[2]; unsigned long long u; } cv;
      cv.h[0] = __float22bfloat162_rn(make_float2(v.x, v.y));
      cv.h[1] = __float22bfloat162_rn(make_float2(v.z, v.w));
      *(unsigned long long*)&Al[r*72 + q*4] = cv.u;
    }
    __syncthreads();
    #pragma unroll
    for (int kh = 0; kh < 2; ++kh) {
      bf16x8 af[4], bfr[4];
      #pragma unroll
      for (int mf = 0; mf < 4; ++mf) {
        int row = wm*64 + mf*16 + lane15;
        af[mf] = *(const bf16x8*)&Al[row*72 + kh*32 + kg*8];
      }
      #pragma unroll
      for (int nf = 0; nf < 4; ++nf) {
        int nl = wn*64 + nf*16 + lane15;
        int jj = kh*4 + kg;
        bfr[nf] = *(const bf16x8*)&Bl[nl*64 + ((jj ^ (nl & 7)) << 3)];
      }
      #pragma unroll
      for (int mf = 0; mf < 4; ++mf)
        #pragma unroll
        for (int nf = 0; nf < 4; ++nf)
          acc[mf][nf] = __builtin_amdgcn_mfma_f32_16x16x32_bf16(af[mf], bfr[nf], acc[mf][nf], 0, 0, 0);
    }
    __syncthreads();
  }

  int bidx = m0 >> 11;
  float dpv[4], vwv[4];
  #pragma unroll
  for (int nf = 0; nf < 4; ++nf) {
    int n = n0 + wn*64 + nf*16 + lane15;
    dpv[nf] = dpb[bidx*HD + n];
    vwv[nf] = vw[n];
  }
  if (tid < 128) red[tid] = 0.0f;
  __syncthreads();
  #pragma unroll
  for (int mf = 0; mf < 4; ++mf) {
    #pragma unroll
    for (int r = 0; r < 4; ++r) {
      float s = 0.0f;
      #pragma unroll
      for (int nf = 0; nf < 4; ++nf) {
        float x = acc[mf][nf][r] + dpv[nf];
        s += tanh_fast(x) * vwv[nf];
      }
      s += __shfl_xor(s, 1); s += __shfl_xor(s, 2);
      s += __shfl_xor(s, 4); s += __shfl_xor(s, 8);
      if (lane15 == 0) atomicAdd(&red[wm*64 + mf*16 + kg*4 + r], s);
    }
  }
  __syncthreads();
  if (tid < 128) atomicAdd(&logits[m0 + tid], red[tid]);
}

// ---------------------------------------------------------------------------
// Kernel 4: masked softmax over S per batch row.  mask==1 -> -1e10
// ---------------------------------------------------------------------------
__global__ void softmax_k(const float* __restrict__ logits, const int* __restrict__ mask,
                          float* __restrict__ out) {
  __shared__ float smax[4];
  __shared__ float ssum[4];
  int tid = threadIdx.x, lane = tid & 63, wid = tid >> 6;
  int b = blockIdx.x;
  const float* lg = logits + b*SS;
  const int*   mk = mask   + b*SS;
  f32x4 l0 = *(const f32x4*)(lg + tid*8);
  f32x4 l1 = *(const f32x4*)(lg + tid*8 + 4);
  i32x4 q0 = *(const i32x4*)(mk + tid*8);
  i32x4 q1 = *(const i32x4*)(mk + tid*8 + 4);
  float v[8];
  v[0] = (q0.x == 1) ? NEGV : l0.x;  v[1] = (q0.y == 1) ? NEGV : l0.y;
  v[2] = (q0.z == 1) ? NEGV : l0.z;  v[3] = (q0.w == 1) ? NEGV : l0.w;
  v[4] = (q1.x == 1) ? NEGV : l1.x;  v[5] = (q1.y == 1) ? NEGV : l1.y;
  v[6] = (q1.z == 1) ? NEGV : l1.z;  v[7] = (q1.w == 1) ? NEGV : l1.w;
  float mx = v[0];
  #pragma unroll
  for (int i = 1; i < 8; ++i) mx = fmaxf(mx, v[i]);
  #pragma unroll
  for (int m = 1; m <= 32; m <<= 1) mx = fmaxf(mx, __shfl_xor(mx, m));
  if (lane == 0) smax[wid] = mx;
  __syncthreads();
  mx = fmaxf(fmaxf(smax[0], smax[1]), fmaxf(smax[2], smax[3]));
  float s = 0.0f;
  #pragma unroll
  for (int i = 0; i < 8; ++i) { v[i] = __expf(v[i] - mx); s += v[i]; }
  #pragma unroll
  for (int m = 1; m <= 32; m <<= 1) s += __shfl_xor(s, m);
  if (lane == 0) ssum[wid] = s;
  __syncthreads();
  s = ssum[0] + ssum[1] + ssum[2] + ssum[3];
  float inv = 1.0f / s;
  f32x4 o0 = {v[0]*inv, v[1]*inv, v[2]*inv, v[3]*inv};
  f32x4 o1 = {v[4]*inv, v[5]*inv, v[6]*inv, v[7]*inv};
  *(f32x4*)(out + b*SS + tid*8)     = o0;
  *(f32x4*)(out + b*SS + tid*8 + 4) = o1;
}

// ---------------------------------------------------------------------------
extern "C" void kernel_launch(void* const* d_in, const int* in_sizes, int n_in,
                              void* d_out, int out_size, void* d_ws, size_t ws_size,
                              hipStream_t stream) {
  const float* dec   = (const float*)d_in[0];   // (B, H)
  const float* enc   = (const float*)d_in[1];   // (B, S, H)
  const int*   mask  = (const int*)  d_in[2];   // (B, S)
  const float* Wattn = (const float*)d_in[3];   // (2H, H)
  const float* battn = (const float*)d_in[4];   // (H)
  const float* vw    = (const float*)d_in[5];   // (H)
  float* out = (float*)d_out;

  const size_t EBF_BYTES = (size_t)MT * HD * 2;             // 268435456
  const size_t FAST_NEED = EBF_BYTES + (2u<<20) + (256u<<10) + (512u<<10);

  char* ws = (char*)d_ws;
  if (ws_size >= FAST_NEED) {
    __hip_bfloat16* ebf = (__hip_bfloat16*)ws;
    __hip_bfloat16* wet = (__hip_bfloat16*)(ws + EBF_BYTES);
    float* dpb    = (float*)(ws + EBF_BYTES + (2u<<20));
    float* logits = (float*)(ws + EBF_BYTES + (2u<<20) + (256u<<10));

    prep_E <<<16384, 256, 0, stream>>>(enc, ebf);
    prep_we<<<128, 256, 0, stream>>>(Wattn, wet);
    prep_dpb<<<dim3(16, 64), 256, 0, stream>>>(dec, Wattn, battn, dpb);
    hipMemsetAsync(logits, 0, (size_t)MT*sizeof(float), stream);
    gemm_fused_bf<<<8192, 256, 0, stream>>>(ebf, wet, dpb, vw, logits);
    softmax_k<<<BB, 256, 0, stream>>>(logits, mask, out);
  } else {
    __hip_bfloat16* wet = (__hip_bfloat16*)ws;
    float* dpb    = (float*)(ws + (2u<<20));
    float* logits = (float*)(ws + (2u<<20) + (256u<<10));

    prep_we<<<128, 256, 0, stream>>>(Wattn, wet);
    prep_dpb<<<dim3(16, 64), 256, 0, stream>>>(dec, Wattn, battn, dpb);
    hipMemsetAsync(logits, 0, (size_t)MT*sizeof(float), stream);
    gemm_fused_f32<<<8192, 256, 0, stream>>>(enc, wet, dpb, vw, logits);
    softmax_k<<<BB, 256, 0, stream>>>(logits, mask, out);
  }
}